// Round 14
// baseline (67.555 us; speedup 1.0000x reference)
//
#include <hip/hip_runtime.h>
#include <hip/hip_fp16.h>

#define NPTS 262144
#define EMB  256
#define NROWS 2048

typedef _Float16 half_t;
typedef __attribute__((ext_vector_type(8))) _Float16 half8;
typedef __attribute__((ext_vector_type(2))) _Float16 half2v;

// ---------------------------------------------------------------------------
// Kernel 1: T2[a,i,o] = (30/4)/(2pi) * sum_e tables[a,i,e] * W1[o,e], fp16.
// ---------------------------------------------------------------------------
__global__ __launch_bounds__(256) void t2_precompute_kernel(
    const float* __restrict__ tables,   // [4][512][256]
    const float* __restrict__ W1,       // [256][256]
    half_t* __restrict__ T2)            // [2048][256]
{
    __shared__ __align__(16) float arow[8][EMB];
    const int row0 = blockIdx.x * 8;
    const int o = threadIdx.x;

    #pragma unroll
    for (int r = 0; r < 8; ++r)
        arow[r][o] = tables[(row0 + r) * EMB + o];
    __syncthreads();

    float acc[8] = {0.f, 0.f, 0.f, 0.f, 0.f, 0.f, 0.f, 0.f};
    const float4* __restrict__ w1v = reinterpret_cast<const float4*>(W1 + o * EMB);
    for (int ec = 0; ec < EMB / 4; ++ec) {
        const float4 w4 = w1v[ec];
        #pragma unroll
        for (int r = 0; r < 8; ++r) {
            const float4 a4 = *reinterpret_cast<const float4*>(&arow[r][ec * 4]);
            acc[r] = fmaf(w4.x, a4.x, acc[r]);
            acc[r] = fmaf(w4.y, a4.y, acc[r]);
            acc[r] = fmaf(w4.z, a4.z, acc[r]);
            acc[r] = fmaf(w4.w, a4.w, acc[r]);
        }
    }
    const float s = 7.5f * 0.15915494309189535f;   // (30/4)/(2pi)
    #pragma unroll
    for (int r = 0; r < 8; ++r)
        T2[(row0 + r) * EMB + o] = (half_t)(s * acc[r]);
}

// ---------------------------------------------------------------------------
// DPP butterfly add over 16 lanes — 1 instruction per step, VALU pipe.
// ---------------------------------------------------------------------------
template <int CTRL>
__device__ __forceinline__ float dpp_add(float v) {
    const int vi = __builtin_bit_cast(int, v);
    const int sh = __builtin_amdgcn_update_dpp(0, vi, CTRL, 0xF, 0xF, true);
    return v + __builtin_bit_cast(float, sh);
}
__device__ __forceinline__ float reduce16(float v) {
    v = dpp_add<0xB1>(v);    // quad_perm xor1
    v = dpp_add<0x4E>(v);    // quad_perm xor2
    v = dpp_add<0x141>(v);   // row_half_mirror
    v = dpp_add<0x140>(v);   // row_mirror
    return v;
}

// ---------------------------------------------------------------------------
// Kernel 2: 16 lanes/point, 4 points/wave, 4 quads/wave (grid 4096; 16384
// waves). NO software pipeline — latency hiding comes from 8 waves/SIMD,
// forced by __launch_bounds__(256, 8) (VGPR <= 64; 68 halves residency).
// ---------------------------------------------------------------------------
__global__ __launch_bounds__(256, 8) void eval_kernel(
    const float* __restrict__ coords,      // [N][2]
    const half_t* __restrict__ T2,         // [2048][256]
    const float* __restrict__ b1,
    const float* __restrict__ W2,
    const float* __restrict__ b2,
    float* __restrict__ out)
{
    const int lane = threadIdx.x & 63;
    const int g    = lane >> 4;            // point slot within wave
    const int l16  = lane & 15;
    const int dA   = l16 * 8;              // dims dA..dA+7   (row half A)
    const int dB   = 128 + l16 * 8;        // dims dB..dB+7   (row half B)

    const int wave   = blockIdx.x * 4 + (threadIdx.x >> 6);  // 0..16383
    const int stride = gridDim.x * 4;                        // 16384

    // ---- hoisted per-lane constants ----
    const float sb = 30.f * 0.15915494309189535f;
    half8 biasA, biasB;
    #pragma unroll
    for (int i = 0; i < 8; ++i) {
        biasA[i] = (half_t)(sb * b1[dA + i]);
        biasB[i] = (half_t)(sb * b1[dB + i]);
    }
    half2v w2A[3][4], w2B[3][4];
    #pragma unroll
    for (int j = 0; j < 3; ++j)
        #pragma unroll
        for (int k = 0; k < 4; ++k) {
            w2A[j][k][0] = (half_t)W2[j * EMB + dA + 2 * k];
            w2A[j][k][1] = (half_t)W2[j * EMB + dA + 2 * k + 1];
            w2B[j][k][0] = (half_t)W2[j * EMB + dB + 2 * k];
            w2B[j][k][1] = (half_t)W2[j * EMB + dB + 2 * k + 1];
        }
    const float ob0 = b2[0], ob1 = b2[1], ob2 = b2[2];

    int Ca[4];
    #pragma unroll
    for (int a = 0; a < 4; ++a) Ca[a] = (a << 18) + (l16 << 4);

    const char* __restrict__ T2b = reinterpret_cast<const char*>(T2);
    const float TMAX = 0.9995f * 511.0f;

    #pragma unroll
    for (int k = 0; k < 4; ++k) {
        const int p = 4 * (wave + k * stride) + g;
        const float2 cf = *reinterpret_cast<const float2*>(coords + 2 * p);
        const float txr = __builtin_amdgcn_fmed3f(fmaf(cf.x, 255.5f, 255.5f), 0.f, 511.f);
        const float tyr = __builtin_amdgcn_fmed3f(fmaf(cf.y, 255.5f, 255.5f), 0.f, 511.f);
        float t[4];
        t[0] = fminf(txr, TMAX);
        t[1] = fminf(tyr, TMAX);
        t[2] = fminf((txr + tyr) * 0.5f, TMAX);
        t[3] = fminf(fmaf(txr - tyr, 0.5f, 255.5f), TMAX);

        int rb[4];
        half2v pw[4];
        #pragma unroll
        for (int a = 0; a < 4; ++a) {
            const int i0 = (int)t[a];
            const float w = t[a] - (float)i0;
            rb[a] = (i0 << 9) + Ca[a];
            pw[a] = __builtin_bit_cast(half2v,
                        __builtin_amdgcn_cvt_pkrtz(1.f - w, w));
        }

        // 16 dense 16B loads (rows i0 / i0+1, halves A / B)
        half8 A0[4], A1[4], B0[4], B1[4];
        #pragma unroll
        for (int a = 0; a < 4; ++a) {
            const char* base = T2b + rb[a];
            A0[a] = *reinterpret_cast<const half8*>(base);
            B0[a] = *reinterpret_cast<const half8*>(base + 256);
            A1[a] = *reinterpret_cast<const half8*>(base + 512);
            B1[a] = *reinterpret_cast<const half8*>(base + 768);
        }

        half8 accA = biasA, accB = biasB;
        #pragma unroll
        for (int a = 0; a < 4; ++a) {
            accA = A0[a] * pw[a][0] + accA;
            accA = A1[a] * pw[a][1] + accA;
            accB = B0[a] * pw[a][0] + accB;
            accB = B1[a] * pw[a][1] + accB;
        }

        float q0 = 0.f, q1 = 0.f, q2 = 0.f;
        #pragma unroll
        for (int kk = 0; kk < 4; ++kk) {
            const float s0 = __builtin_amdgcn_sinf((float)accA[2 * kk]);
            const float s1 = __builtin_amdgcn_sinf((float)accA[2 * kk + 1]);
            const half2v hp = __builtin_bit_cast(half2v,
                                  __builtin_amdgcn_cvt_pkrtz(s0, s1));
            q0 = __builtin_amdgcn_fdot2(hp, w2A[0][kk], q0, false);
            q1 = __builtin_amdgcn_fdot2(hp, w2A[1][kk], q1, false);
            q2 = __builtin_amdgcn_fdot2(hp, w2A[2][kk], q2, false);
        }
        #pragma unroll
        for (int kk = 0; kk < 4; ++kk) {
            const float s0 = __builtin_amdgcn_sinf((float)accB[2 * kk]);
            const float s1 = __builtin_amdgcn_sinf((float)accB[2 * kk + 1]);
            const half2v hp = __builtin_bit_cast(half2v,
                                  __builtin_amdgcn_cvt_pkrtz(s0, s1));
            q0 = __builtin_amdgcn_fdot2(hp, w2B[0][kk], q0, false);
            q1 = __builtin_amdgcn_fdot2(hp, w2B[1][kk], q1, false);
            q2 = __builtin_amdgcn_fdot2(hp, w2B[2][kk], q2, false);
        }

        q0 = reduce16(q0);
        q1 = reduce16(q1);
        q2 = reduce16(q2);

        if (l16 == 0) {
            *reinterpret_cast<float3*>(out + 3 * p) =
                make_float3(q0 + ob0, q1 + ob1, q2 + ob2);
        }
    }
}

extern "C" void kernel_launch(void* const* d_in, const int* in_sizes, int n_in,
                              void* d_out, int out_size, void* d_ws, size_t ws_size,
                              hipStream_t stream) {
    const float* coords = (const float*)d_in[0];
    const float* tables = (const float*)d_in[1];
    const float* W1     = (const float*)d_in[2];
    const float* b1     = (const float*)d_in[3];
    const float* W2     = (const float*)d_in[4];
    const float* b2     = (const float*)d_in[5];
    float* out = (float*)d_out;

    half_t* T2 = (half_t*)d_ws;   // 1 MiB scratch

    hipLaunchKernelGGL(t2_precompute_kernel, dim3(NROWS / 8), dim3(256), 0, stream,
                       tables, W1, T2);
    hipLaunchKernelGGL(eval_kernel, dim3(4096), dim3(256), 0, stream,
                       coords, T2, b1, W2, b2, out);
}

// Round 15
// 56.156 us; speedup vs baseline: 1.2030x; 1.2030x over previous
//
#include <hip/hip_runtime.h>
#include <hip/hip_fp16.h>

#define NPTS 262144
#define EMB  256
#define NROWS 2048

typedef _Float16 half_t;
typedef __attribute__((ext_vector_type(8))) _Float16 half8;
typedef __attribute__((ext_vector_type(2))) _Float16 half2v;

// ---------------------------------------------------------------------------
// Kernel 1: T2[a,i,o] = (30/4)/(2pi) * sum_e tables[a,i,e] * W1[o,e], fp16.
// ---------------------------------------------------------------------------
__global__ __launch_bounds__(256) void t2_precompute_kernel(
    const float* __restrict__ tables,   // [4][512][256]
    const float* __restrict__ W1,       // [256][256]
    half_t* __restrict__ T2)            // [2048][256]
{
    __shared__ __align__(16) float arow[8][EMB];
    const int row0 = blockIdx.x * 8;
    const int o = threadIdx.x;

    #pragma unroll
    for (int r = 0; r < 8; ++r)
        arow[r][o] = tables[(row0 + r) * EMB + o];
    __syncthreads();

    float acc[8] = {0.f, 0.f, 0.f, 0.f, 0.f, 0.f, 0.f, 0.f};
    const float4* __restrict__ w1v = reinterpret_cast<const float4*>(W1 + o * EMB);
    for (int ec = 0; ec < EMB / 4; ++ec) {
        const float4 w4 = w1v[ec];
        #pragma unroll
        for (int r = 0; r < 8; ++r) {
            const float4 a4 = *reinterpret_cast<const float4*>(&arow[r][ec * 4]);
            acc[r] = fmaf(w4.x, a4.x, acc[r]);
            acc[r] = fmaf(w4.y, a4.y, acc[r]);
            acc[r] = fmaf(w4.z, a4.z, acc[r]);
            acc[r] = fmaf(w4.w, a4.w, acc[r]);
        }
    }
    const float s = 7.5f * 0.15915494309189535f;   // (30/4)/(2pi)
    #pragma unroll
    for (int r = 0; r < 8; ++r)
        T2[(row0 + r) * EMB + o] = (half_t)(s * acc[r]);
}

// ---------------------------------------------------------------------------
// DPP butterfly add over 16 lanes — VALU pipe.
// ---------------------------------------------------------------------------
template <int CTRL>
__device__ __forceinline__ float dpp_add(float v) {
    const int vi = __builtin_bit_cast(int, v);
    const int sh = __builtin_amdgcn_update_dpp(0, vi, CTRL, 0xF, 0xF, true);
    return v + __builtin_bit_cast(float, sh);
}
__device__ __forceinline__ float reduce16(float v) {
    v = dpp_add<0xB1>(v);    // quad_perm xor1
    v = dpp_add<0x4E>(v);    // quad_perm xor2
    v = dpp_add<0x141>(v);   // row_half_mirror
    v = dpp_add<0x140>(v);   // row_mirror
    return v;
}

// ---------------------------------------------------------------------------
// Kernel 2: 16 lanes/point, 4 points/wave, 8 quads/wave (grid 2048).
// Pipeline enforced by asm memory fences: plain C++ loads are issued for
// quad j+2, then a volatile "memory"-clobber asm pins them (loads cannot
// sink below a memory barrier); the next body's compute then runs with 16
// loads in flight, gated by the compiler's own vmcnt(16). Two named buffer
// sets; 6 pipelined bodies + 2 peeled consume-only tails (no redundant
// loads). __launch_bounds__(256,2): 256-VGPR budget, no spill.
// ---------------------------------------------------------------------------
__global__ __launch_bounds__(256, 2) void eval_kernel(
    const float* __restrict__ coords,      // [N][2]
    const half_t* __restrict__ T2,         // [2048][256]
    const float* __restrict__ b1,
    const float* __restrict__ W2,
    const float* __restrict__ b2,
    float* __restrict__ out)
{
    const int lane = threadIdx.x & 63;
    const int g    = lane >> 4;            // point slot within wave
    const int l16  = lane & 15;
    const int dA   = l16 * 8;              // dims dA..dA+7   (row half A)
    const int dB   = 128 + l16 * 8;        // dims dB..dB+7   (row half B)

    const int wave  = blockIdx.x * 4 + (threadIdx.x >> 6);  // 0..8191
    const int qbase = wave * 8;

    // ---- hoisted per-lane constants ----
    const float sb = 30.f * 0.15915494309189535f;
    half8 biasA, biasB;
    #pragma unroll
    for (int i = 0; i < 8; ++i) {
        biasA[i] = (half_t)(sb * b1[dA + i]);
        biasB[i] = (half_t)(sb * b1[dB + i]);
    }
    half2v w2A[3][4], w2B[3][4];
    #pragma unroll
    for (int j = 0; j < 3; ++j)
        #pragma unroll
        for (int k = 0; k < 4; ++k) {
            w2A[j][k][0] = (half_t)W2[j * EMB + dA + 2 * k];
            w2A[j][k][1] = (half_t)W2[j * EMB + dA + 2 * k + 1];
            w2B[j][k][0] = (half_t)W2[j * EMB + dB + 2 * k];
            w2B[j][k][1] = (half_t)W2[j * EMB + dB + 2 * k + 1];
        }
    const float ob0 = b2[0], ob1 = b2[1], ob2 = b2[2];

    int Ca[4];
    #pragma unroll
    for (int a = 0; a < 4; ++a) Ca[a] = (a << 18) + (l16 << 4);

    const char* __restrict__ T2b = reinterpret_cast<const char*>(T2);
    const float TMAX = 0.9995f * 511.0f;

    // ---- helpers ----
    auto calcq = [&](int q, int rb[4], half2v pw[4], int& pOut) {
        const int p = 4 * q + g;
        pOut = p;
        const float2 cf = *reinterpret_cast<const float2*>(coords + 2 * p);
        const float txr = __builtin_amdgcn_fmed3f(fmaf(cf.x, 255.5f, 255.5f), 0.f, 511.f);
        const float tyr = __builtin_amdgcn_fmed3f(fmaf(cf.y, 255.5f, 255.5f), 0.f, 511.f);
        float t[4];
        t[0] = fminf(txr, TMAX);
        t[1] = fminf(tyr, TMAX);
        t[2] = fminf((txr + tyr) * 0.5f, TMAX);
        t[3] = fminf(fmaf(txr - tyr, 0.5f, 255.5f), TMAX);
        #pragma unroll
        for (int a = 0; a < 4; ++a) {
            const int i0 = (int)t[a];
            const float w = t[a] - (float)i0;
            rb[a] = (i0 << 9) + Ca[a];
            pw[a] = __builtin_bit_cast(half2v,
                        __builtin_amdgcn_cvt_pkrtz(1.f - w, w));
        }
    };
    auto loadset = [&](const int rb[4], half8 (&A0)[4], half8 (&A1)[4],
                       half8 (&B0)[4], half8 (&B1)[4]) {
        #pragma unroll
        for (int a = 0; a < 4; ++a) {
            const char* base = T2b + rb[a];
            A0[a] = *reinterpret_cast<const half8*>(base);
            B0[a] = *reinterpret_cast<const half8*>(base + 256);
            A1[a] = *reinterpret_cast<const half8*>(base + 512);
            B1[a] = *reinterpret_cast<const half8*>(base + 768);
        }
    };
    auto comp = [&](const half8 (&A0)[4], const half8 (&A1)[4],
                    const half8 (&B0)[4], const half8 (&B1)[4],
                    const half2v (&pw)[4], int p) {
        half8 accA = biasA, accB = biasB;
        #pragma unroll
        for (int a = 0; a < 4; ++a) {
            accA = A0[a] * pw[a][0] + accA;
            accA = A1[a] * pw[a][1] + accA;
            accB = B0[a] * pw[a][0] + accB;
            accB = B1[a] * pw[a][1] + accB;
        }
        float q0r = 0.f, q1r = 0.f, q2r = 0.f;
        #pragma unroll
        for (int k = 0; k < 4; ++k) {
            const float s0 = __builtin_amdgcn_sinf((float)accA[2 * k]);
            const float s1 = __builtin_amdgcn_sinf((float)accA[2 * k + 1]);
            const half2v hp = __builtin_bit_cast(half2v,
                                  __builtin_amdgcn_cvt_pkrtz(s0, s1));
            q0r = __builtin_amdgcn_fdot2(hp, w2A[0][k], q0r, false);
            q1r = __builtin_amdgcn_fdot2(hp, w2A[1][k], q1r, false);
            q2r = __builtin_amdgcn_fdot2(hp, w2A[2][k], q2r, false);
        }
        #pragma unroll
        for (int k = 0; k < 4; ++k) {
            const float s0 = __builtin_amdgcn_sinf((float)accB[2 * k]);
            const float s1 = __builtin_amdgcn_sinf((float)accB[2 * k + 1]);
            const half2v hp = __builtin_bit_cast(half2v,
                                  __builtin_amdgcn_cvt_pkrtz(s0, s1));
            q0r = __builtin_amdgcn_fdot2(hp, w2B[0][k], q0r, false);
            q1r = __builtin_amdgcn_fdot2(hp, w2B[1][k], q1r, false);
            q2r = __builtin_amdgcn_fdot2(hp, w2B[2][k], q2r, false);
        }
        q0r = reduce16(q0r);
        q1r = reduce16(q1r);
        q2r = reduce16(q2r);
        if (l16 == 0) {
            *reinterpret_cast<float3*>(out + 3 * p) =
                make_float3(q0r + ob0, q1r + ob1, q2r + ob2);
        }
    };

    // ---- named buffer sets ----
    half8 A0a[4], A1a[4], B0a[4], B1a[4];
    half8 A0b[4], A1b[4], B0b[4], B1b[4];
    half2v wa[4], wb[4];
    int pa, pb;

    // pipelined body: consume buf, reload buf for quad qn, fence-pin loads
    auto step = [&](half8 (&A0)[4], half8 (&A1)[4],
                    half8 (&B0)[4], half8 (&B1)[4],
                    half2v (&pw)[4], int& pp, int qn) {
        int rbn[4]; half2v wn[4]; int pn;
        calcq(qn, rbn, wn, pn);
        comp(A0, A1, B0, B1, pw, pp);    // vmcnt(16): other buf in flight
        loadset(rbn, A0, A1, B0, B1);    // issue 16 loads for quad qn
        asm volatile("" ::: "memory");   // loads may NOT sink below this
        #pragma unroll
        for (int a = 0; a < 4; ++a) pw[a] = wn[a];
        pp = pn;
    };

    // ---- prologue: quads 0,1 in flight ----
    {
        int rb[4];
        calcq(qbase + 0, rb, wa, pa);
        loadset(rb, A0a, A1a, B0a, B1a);
        asm volatile("" ::: "memory");
        calcq(qbase + 1, rb, wb, pb);
        loadset(rb, A0b, A1b, B0b, B1b);
        asm volatile("" ::: "memory");
    }

    // ---- 6 pipelined bodies (consume q0..q5, load q2..q7) ----
    step(A0a, A1a, B0a, B1a, wa, pa, qbase + 2);
    step(A0b, A1b, B0b, B1b, wb, pb, qbase + 3);
    step(A0a, A1a, B0a, B1a, wa, pa, qbase + 4);
    step(A0b, A1b, B0b, B1b, wb, pb, qbase + 5);
    step(A0a, A1a, B0a, B1a, wa, pa, qbase + 6);
    step(A0b, A1b, B0b, B1b, wb, pb, qbase + 7);

    // ---- peeled tails: consume q6, q7 (no reload) ----
    comp(A0a, A1a, B0a, B1a, wa, pa);
    comp(A0b, A1b, B0b, B1b, wb, pb);
}

extern "C" void kernel_launch(void* const* d_in, const int* in_sizes, int n_in,
                              void* d_out, int out_size, void* d_ws, size_t ws_size,
                              hipStream_t stream) {
    const float* coords = (const float*)d_in[0];
    const float* tables = (const float*)d_in[1];
    const float* W1     = (const float*)d_in[2];
    const float* b1     = (const float*)d_in[3];
    const float* W2     = (const float*)d_in[4];
    const float* b2     = (const float*)d_in[5];
    float* out = (float*)d_out;

    half_t* T2 = (half_t*)d_ws;   // 1 MiB scratch

    hipLaunchKernelGGL(t2_precompute_kernel, dim3(NROWS / 8), dim3(256), 0, stream,
                       tables, W1, T2);
    hipLaunchKernelGGL(eval_kernel, dim3(2048), dim3(256), 0, stream,
                       coords, T2, b1, W2, b2, out);
}